// Round 1
// baseline (274.049 us; speedup 1.0000x reference)
//
#include <hip/hip_runtime.h>

// ---- problem constants (match reference) ----
#define N_HALF   131072
#define MEM_ELEMS (64 * 512)
#define NIN      (2 * N_HALF + MEM_ELEMS + 1)   // 294913 input nodes (incl. bias)
#define NEDGES   16777216
#define NOUT     512
#define TPB      256
#define NBLK1    2048
#define GROUPS_PER_BLOCK (NEDGES / NBLK1 / 4)   // 2048 int4-groups per block
#define ITERS    (GROUPS_PER_BLOCK / TPB)       // 8

// ---------------------------------------------------------------
// Stage 0: build flat activation vector x = [terrain, population,
//          memory.flatten(), 1.0]
// ---------------------------------------------------------------
__global__ __launch_bounds__(TPB) void build_x_kernel(
    const float* __restrict__ terrain,
    const float* __restrict__ pop,
    const float* __restrict__ mem,
    float* __restrict__ x)
{
    int i = blockIdx.x * TPB + threadIdx.x;
    if (i >= NIN) return;
    float v;
    if (i < N_HALF)            v = terrain[i];
    else if (i < 2 * N_HALF)   v = pop[i - N_HALF];
    else if (i < NIN - 1)      v = mem[i - 2 * N_HALF];
    else                       v = 1.0f;
    x[i] = v;
}

__device__ __forceinline__ float fetch_direct(int s,
    const float* __restrict__ terrain,
    const float* __restrict__ pop,
    const float* __restrict__ mem)
{
    if (s < 2 * N_HALF)
        return (s < N_HALF) ? terrain[s] : pop[s - N_HALF];
    return (s < NIN - 1) ? mem[s - 2 * N_HALF] : 1.0f;
}

__global__ __launch_bounds__(TPB) void zero_out_kernel(float* __restrict__ out)
{
    int i = blockIdx.x * TPB + threadIdx.x;
    if (i < NOUT) out[i] = 0.0f;
}

// ---------------------------------------------------------------
// Stage 1: per-edge gather-multiply, scatter-add into per-block LDS
// accumulator, then emit per-block partials (MODE 0) or global
// atomics (MODE 1/2 fallbacks).
//   MODE 0: x prebuilt in ws, write partials[block][512]
//   MODE 1: x prebuilt in ws, unsafeAtomicAdd into out
//   MODE 2: direct 3-way gather, unsafeAtomicAdd into out
// ---------------------------------------------------------------
template <int MODE>
__global__ __launch_bounds__(TPB) void edge_kernel(
    const int4*   __restrict__ src4,
    const int4*   __restrict__ dst4,
    const float4* __restrict__ w4,
    const float*  __restrict__ x,
    const float*  __restrict__ terrain,
    const float*  __restrict__ pop,
    const float*  __restrict__ mem,
    float* __restrict__ outp)
{
    __shared__ float acc[NOUT];
    const int t = threadIdx.x;
    acc[t] = 0.0f;
    acc[t + TPB] = 0.0f;
    __syncthreads();

    const int base = blockIdx.x * GROUPS_PER_BLOCK + t;
#pragma unroll
    for (int j = 0; j < ITERS; ++j) {
        const int g = base + j * TPB;
        const int4   s = src4[g];
        const int4   d = dst4[g];
        const float4 w = w4[g];
        float vx, vy, vz, vw;
        if (MODE == 2) {
            vx = fetch_direct(s.x, terrain, pop, mem);
            vy = fetch_direct(s.y, terrain, pop, mem);
            vz = fetch_direct(s.z, terrain, pop, mem);
            vw = fetch_direct(s.w, terrain, pop, mem);
        } else {
            vx = x[s.x];
            vy = x[s.y];
            vz = x[s.z];
            vw = x[s.w];
        }
        unsafeAtomicAdd(&acc[d.x], vx * w.x);
        unsafeAtomicAdd(&acc[d.y], vy * w.y);
        unsafeAtomicAdd(&acc[d.z], vz * w.z);
        unsafeAtomicAdd(&acc[d.w], vw * w.w);
    }
    __syncthreads();

    if (MODE == 0) {
        outp[(size_t)blockIdx.x * NOUT + t]       = acc[t];
        outp[(size_t)blockIdx.x * NOUT + t + TPB] = acc[t + TPB];
    } else {
        unsafeAtomicAdd(&outp[t],       acc[t]);
        unsafeAtomicAdd(&outp[t + TPB], acc[t + TPB]);
    }
}

// ---------------------------------------------------------------
// Stage 2: reduce partials[NBLK1][512] -> out[512].
// 128 blocks; block b owns outputs 4b..4b+3 (one float4 column).
// ---------------------------------------------------------------
__global__ __launch_bounds__(TPB) void reduce_kernel(
    const float* __restrict__ partials, float* __restrict__ out)
{
    const float4* __restrict__ p4 = (const float4*)partials;
    const int t = threadIdx.x;
    float4 s = make_float4(0.f, 0.f, 0.f, 0.f);
    for (int k = t; k < NBLK1; k += TPB) {
        float4 v = p4[(size_t)k * (NOUT / 4) + blockIdx.x];
        s.x += v.x; s.y += v.y; s.z += v.z; s.w += v.w;
    }
#pragma unroll
    for (int off = 32; off; off >>= 1) {
        s.x += __shfl_down(s.x, off, 64);
        s.y += __shfl_down(s.y, off, 64);
        s.z += __shfl_down(s.z, off, 64);
        s.w += __shfl_down(s.w, off, 64);
    }
    __shared__ float l[4][4];
    const int wid = t >> 6, lane = t & 63;
    if (lane == 0) {
        l[wid][0] = s.x; l[wid][1] = s.y; l[wid][2] = s.z; l[wid][3] = s.w;
    }
    __syncthreads();
    if (t < 4) {
        out[blockIdx.x * 4 + t] = l[0][t] + l[1][t] + l[2][t] + l[3][t];
    }
}

extern "C" void kernel_launch(void* const* d_in, const int* in_sizes, int n_in,
                              void* d_out, int out_size, void* d_ws, size_t ws_size,
                              hipStream_t stream)
{
    const float* terrain = (const float*)d_in[0];
    const float* pop     = (const float*)d_in[1];
    const float* mem     = (const float*)d_in[2];
    const int*   src     = (const int*)d_in[3];
    const int*   dst     = (const int*)d_in[4];
    const float* w       = (const float*)d_in[5];
    float* out = (float*)d_out;

    const size_t X_BYTES  = (size_t)NIN * 4;                  // 1,179,652
    const size_t PART_OFF = 1179904;                          // X_BYTES rounded to 256
    const size_t NEED     = PART_OFF + (size_t)NBLK1 * NOUT * 4;  // ~5.4 MB

    float* x        = (float*)d_ws;
    float* partials = (float*)((char*)d_ws + PART_OFF);

    if (ws_size >= NEED) {
        build_x_kernel<<<(NIN + TPB - 1) / TPB, TPB, 0, stream>>>(terrain, pop, mem, x);
        edge_kernel<0><<<NBLK1, TPB, 0, stream>>>(
            (const int4*)src, (const int4*)dst, (const float4*)w,
            x, terrain, pop, mem, partials);
        reduce_kernel<<<NOUT / 4, TPB, 0, stream>>>(partials, out);
    } else if (ws_size >= X_BYTES) {
        build_x_kernel<<<(NIN + TPB - 1) / TPB, TPB, 0, stream>>>(terrain, pop, mem, x);
        zero_out_kernel<<<(NOUT + TPB - 1) / TPB, TPB, 0, stream>>>(out);
        edge_kernel<1><<<NBLK1, TPB, 0, stream>>>(
            (const int4*)src, (const int4*)dst, (const float4*)w,
            x, terrain, pop, mem, out);
    } else {
        zero_out_kernel<<<(NOUT + TPB - 1) / TPB, TPB, 0, stream>>>(out);
        edge_kernel<2><<<NBLK1, TPB, 0, stream>>>(
            (const int4*)src, (const int4*)dst, (const float4*)w,
            nullptr, terrain, pop, mem, out);
    }
}

// Round 3
// 266.939 us; speedup vs baseline: 1.0266x; 1.0266x over previous
//
#include <hip/hip_runtime.h>

// ---- problem constants (match reference) ----
#define N_HALF   131072
#define MEM_ELEMS (64 * 512)
#define NIN      (2 * N_HALF + MEM_ELEMS + 1)   // 294913 input nodes (incl. bias)
#define NEDGES   16777216
#define NOUT     512
#define TPB      256
#define NBLK1    2048
#define GROUPS_PER_BLOCK (NEDGES / NBLK1 / 4)   // 2048 int4-groups per block
#define ITERS    (GROUPS_PER_BLOCK / TPB)       // 8 groups (32 edges) per thread
#define BATCH    4                              // int4-groups per pipelined batch
#define NBATCH   (ITERS / BATCH)                // 2

// reduce params
#define RBLK          128
#define ROWS_PER_BLK  (NBLK1 / RBLK)            // 16

// clang native vectors (accepted by __builtin_nontemporal_load)
typedef int   vint4   __attribute__((ext_vector_type(4)));
typedef float vfloat4 __attribute__((ext_vector_type(4)));

// ---------------------------------------------------------------
// Stage 0: build x = [terrain, population, memory.flatten(), 1.0]
// and zero the 512-float output (atomically accumulated later).
// ---------------------------------------------------------------
__global__ __launch_bounds__(TPB) void build_x_kernel(
    const float* __restrict__ terrain,
    const float* __restrict__ pop,
    const float* __restrict__ mem,
    float* __restrict__ x,
    float* __restrict__ out)
{
    int i = blockIdx.x * TPB + threadIdx.x;
    if (i < NOUT) out[i] = 0.0f;
    if (i >= NIN) return;
    float v;
    if (i < N_HALF)            v = terrain[i];
    else if (i < 2 * N_HALF)   v = pop[i - N_HALF];
    else if (i < NIN - 1)      v = mem[i - 2 * N_HALF];
    else                       v = 1.0f;
    x[i] = v;
}

__device__ __forceinline__ float fetch_direct(int s,
    const float* __restrict__ terrain,
    const float* __restrict__ pop,
    const float* __restrict__ mem)
{
    if (s < 2 * N_HALF)
        return (s < N_HALF) ? terrain[s] : pop[s - N_HALF];
    return (s < NIN - 1) ? mem[s - 2 * N_HALF] : 1.0f;
}

__global__ __launch_bounds__(TPB) void zero_out_kernel(float* __restrict__ out)
{
    int i = blockIdx.x * TPB + threadIdx.x;
    if (i < NOUT) out[i] = 0.0f;
}

// ---------------------------------------------------------------
// Stage 1: gather-multiply-scatter with explicit register batching.
//   Per batch: 12 non-temporal stream loads (src/dst/w x4) staged
//   in registers, 16 gathers issued together; next batch's streams
//   issue while current gathers are in flight (software pipeline).
//   MODE 0: write per-block partials.  MODE 1: global atomics.
//   MODE 2: no-x fallback, direct 3-way gather + global atomics.
// ---------------------------------------------------------------
template <int MODE>
__global__ __launch_bounds__(TPB) void edge_kernel(
    const vint4*   __restrict__ src4,
    const vint4*   __restrict__ dst4,
    const vfloat4* __restrict__ w4,
    const float*   __restrict__ x,
    const float*   __restrict__ terrain,
    const float*   __restrict__ pop,
    const float*   __restrict__ mem,
    float* __restrict__ outp)
{
    __shared__ float acc[NOUT];
    const int t = threadIdx.x;
    acc[t] = 0.0f;
    acc[t + TPB] = 0.0f;
    __syncthreads();

    const int base = blockIdx.x * GROUPS_PER_BLOCK + t;

    vint4   s[BATCH], d[BATCH];
    vfloat4 wv[BATCH];
    // Prologue: stage batch 0 streams (src first so gathers can start).
#pragma unroll
    for (int u = 0; u < BATCH; ++u)
        s[u] = __builtin_nontemporal_load(&src4[base + u * TPB]);
#pragma unroll
    for (int u = 0; u < BATCH; ++u)
        d[u] = __builtin_nontemporal_load(&dst4[base + u * TPB]);
#pragma unroll
    for (int u = 0; u < BATCH; ++u)
        wv[u] = __builtin_nontemporal_load(&w4[base + u * TPB]);

#pragma unroll
    for (int b = 0; b < NBATCH; ++b) {
        // Issue all 16 gathers for this batch.
        float g[BATCH][4];
#pragma unroll
        for (int u = 0; u < BATCH; ++u) {
            if (MODE == 2) {
                g[u][0] = fetch_direct(s[u].x, terrain, pop, mem);
                g[u][1] = fetch_direct(s[u].y, terrain, pop, mem);
                g[u][2] = fetch_direct(s[u].z, terrain, pop, mem);
                g[u][3] = fetch_direct(s[u].w, terrain, pop, mem);
            } else {
                g[u][0] = x[s[u].x];
                g[u][1] = x[s[u].y];
                g[u][2] = x[s[u].z];
                g[u][3] = x[s[u].w];
            }
        }

        // Stage next batch's streams while gathers are in flight.
        vint4   s2[BATCH], d2[BATCH];
        vfloat4 w2[BATCH];
        if (b + 1 < NBATCH) {
            const int nb = base + (b + 1) * BATCH * TPB;
#pragma unroll
            for (int u = 0; u < BATCH; ++u)
                s2[u] = __builtin_nontemporal_load(&src4[nb + u * TPB]);
#pragma unroll
            for (int u = 0; u < BATCH; ++u)
                d2[u] = __builtin_nontemporal_load(&dst4[nb + u * TPB]);
#pragma unroll
            for (int u = 0; u < BATCH; ++u)
                w2[u] = __builtin_nontemporal_load(&w4[nb + u * TPB]);
        }

        // Consume current batch: FMA + LDS scatter-add.
#pragma unroll
        for (int u = 0; u < BATCH; ++u) {
            unsafeAtomicAdd(&acc[d[u].x], g[u][0] * wv[u].x);
            unsafeAtomicAdd(&acc[d[u].y], g[u][1] * wv[u].y);
            unsafeAtomicAdd(&acc[d[u].z], g[u][2] * wv[u].z);
            unsafeAtomicAdd(&acc[d[u].w], g[u][3] * wv[u].w);
        }

        // Rotate pipeline registers.
        if (b + 1 < NBATCH) {
#pragma unroll
            for (int u = 0; u < BATCH; ++u) {
                s[u] = s2[u]; d[u] = d2[u]; wv[u] = w2[u];
            }
        }
    }
    __syncthreads();

    if (MODE == 0) {
        outp[(size_t)blockIdx.x * NOUT + t]       = acc[t];
        outp[(size_t)blockIdx.x * NOUT + t + TPB] = acc[t + TPB];
    } else {
        unsafeAtomicAdd(&outp[t],       acc[t]);
        unsafeAtomicAdd(&outp[t + TPB], acc[t + TPB]);
    }
}

// ---------------------------------------------------------------
// Stage 2: reduce partials[NBLK1][512] -> out[512], coalesced.
// Block b owns rows [b*16, b*16+16); thread t owns float4 column t.
// Per row, 128 threads read one contiguous 2 KB line. Finish with
// 4 global atomic adds per thread into the pre-zeroed out.
// ---------------------------------------------------------------
__global__ __launch_bounds__(128) void reduce_kernel(
    const float* __restrict__ partials, float* __restrict__ out)
{
    const vfloat4* __restrict__ p4 = (const vfloat4*)partials;
    const int t  = threadIdx.x;                 // 0..127 float4-column
    const int r0 = blockIdx.x * ROWS_PER_BLK;
    vfloat4 s = {0.f, 0.f, 0.f, 0.f};
#pragma unroll
    for (int r = 0; r < ROWS_PER_BLK; ++r) {
        vfloat4 v = p4[(size_t)(r0 + r) * (NOUT / 4) + t];
        s += v;
    }
    unsafeAtomicAdd(&out[t * 4 + 0], s.x);
    unsafeAtomicAdd(&out[t * 4 + 1], s.y);
    unsafeAtomicAdd(&out[t * 4 + 2], s.z);
    unsafeAtomicAdd(&out[t * 4 + 3], s.w);
}

extern "C" void kernel_launch(void* const* d_in, const int* in_sizes, int n_in,
                              void* d_out, int out_size, void* d_ws, size_t ws_size,
                              hipStream_t stream)
{
    const float* terrain = (const float*)d_in[0];
    const float* pop     = (const float*)d_in[1];
    const float* mem     = (const float*)d_in[2];
    const int*   src     = (const int*)d_in[3];
    const int*   dst     = (const int*)d_in[4];
    const float* w       = (const float*)d_in[5];
    float* out = (float*)d_out;

    const size_t X_BYTES  = (size_t)NIN * 4;                      // 1,179,652
    const size_t PART_OFF = 1179904;                              // X_BYTES -> 256B align
    const size_t NEED     = PART_OFF + (size_t)NBLK1 * NOUT * 4;  // ~5.4 MB

    float* x        = (float*)d_ws;
    float* partials = (float*)((char*)d_ws + PART_OFF);

    if (ws_size >= NEED) {
        build_x_kernel<<<(NIN + TPB - 1) / TPB, TPB, 0, stream>>>(terrain, pop, mem, x, out);
        edge_kernel<0><<<NBLK1, TPB, 0, stream>>>(
            (const vint4*)src, (const vint4*)dst, (const vfloat4*)w,
            x, terrain, pop, mem, partials);
        reduce_kernel<<<RBLK, 128, 0, stream>>>(partials, out);
    } else if (ws_size >= X_BYTES) {
        build_x_kernel<<<(NIN + TPB - 1) / TPB, TPB, 0, stream>>>(terrain, pop, mem, x, out);
        edge_kernel<1><<<NBLK1, TPB, 0, stream>>>(
            (const vint4*)src, (const vint4*)dst, (const vfloat4*)w,
            x, terrain, pop, mem, out);
    } else {
        zero_out_kernel<<<(NOUT + TPB - 1) / TPB, TPB, 0, stream>>>(out);
        edge_kernel<2><<<NBLK1, TPB, 0, stream>>>(
            (const vint4*)src, (const vint4*)dst, (const vfloat4*)w,
            nullptr, terrain, pop, mem, out);
    }
}